// Round 5
// baseline (439.184 us; speedup 1.0000x reference)
//
#include <hip/hip_runtime.h>
#include <hip/hip_bf16.h>

typedef __bf16 bf16x8 __attribute__((ext_vector_type(8)));
typedef float f32x4 __attribute__((ext_vector_type(4)));
typedef unsigned short u16x8 __attribute__((ext_vector_type(8)));

#define EPS 1e-8f
#define TAU_INV 10.0f

#define BM 128
#define BN 512
#define BK 32
#define MT 8           // BM/16 tiles per wave (wave covers all rows)
#define LSTRIDE 516    // 512 + 4 pad for epilogue fp32 tile

#define ABUF 4096      // u16 per A buffer: 8 tiles * 64 granules * 8
#define BSTEP 16384    // u16 per kt-block in swizzled B (32 tiles * 512)

// ---------------------------------------------------------------------------
// prep: centers -> bf16 in MFMA-granule-swizzled order + inv norms.
// Bsw: granule at ((kt*32 + nt)*64 + (r&15) + q*16)*8 u16 holds
// B[r][kt*32 + q*8 .. +8]. One wave per row; lane i owns k=i*16..+16.
// ---------------------------------------------------------------------------
__global__ __launch_bounds__(256) void prep_centers_kernel(
    const float* __restrict__ cen, unsigned short* __restrict__ Bsw,
    float* __restrict__ inv_c, int K, int D)
{
    const int wave = threadIdx.x >> 6;
    const int lane = threadIdx.x & 63;
    const int row  = blockIdx.x * 4 + wave;
    if (row >= K) return;

    const float* src = cen + (size_t)row * D + lane * 16;
    const int kt = lane >> 1;
    const int nt = row >> 4;
    const int r16 = row & 15;
    const int q0 = (lane & 1) * 2;

    float ss = 0.0f;
    u16x8 g[2];
    #pragma unroll
    for (int h = 0; h < 2; ++h) {
        #pragma unroll
        for (int j = 0; j < 2; ++j) {
            float4 v = *(const float4*)(src + h * 8 + j * 4);
            ss += v.x * v.x + v.y * v.y + v.z * v.z + v.w * v.w;
            g[h][j * 4 + 0] = __builtin_bit_cast(unsigned short, __float2bfloat16(v.x));
            g[h][j * 4 + 1] = __builtin_bit_cast(unsigned short, __float2bfloat16(v.y));
            g[h][j * 4 + 2] = __builtin_bit_cast(unsigned short, __float2bfloat16(v.z));
            g[h][j * 4 + 3] = __builtin_bit_cast(unsigned short, __float2bfloat16(v.w));
        }
        size_t off = ((size_t)(kt * 32 + nt) * 64 + r16 + (q0 + h) * 16) * 8;
        *(u16x8*)(Bsw + off) = g[h];
    }
    #pragma unroll
    for (int off = 32; off; off >>= 1) ss += __shfl_xor(ss, off);
    if (lane == 0)
        inv_c[row] = (1.0f / fmaxf(sqrtf(ss), EPS)) * TAU_INV;
}

// ---------------------------------------------------------------------------
// fused GEMM + log-softmax + NLL.
// block = 128 rows x all 512 centers; 512 threads = 8 waves.
// Wave tile = 128x64.  B: global(L2)->VGPR double-buffered, never in LDS.
// A: fp32 global -> bf16 -> LDS (granule layout, XOR swizzle), double-buffered.
// ---------------------------------------------------------------------------
__global__ __launch_bounds__(512, 2) void gemm_loss_kernel(
    const float* __restrict__ Afp, const unsigned short* __restrict__ Bsw,
    const float* __restrict__ inv_c, const int* __restrict__ labels,
    float* __restrict__ out, int N, int D)
{
    __shared__ union {
        unsigned short A[2 * ABUF];    // 2 x 8KB bf16 A tiles
        float L[16 * LSTRIDE];         // epilogue overlay (33 KB)
    } sm;
    __shared__ float inv_e_s[BM];
    __shared__ float blockLoss;

    const int tid  = threadIdx.x;
    const int wave = tid >> 6;
    const int lane = tid & 63;
    const int quad = lane >> 4;
    const int tq   = lane & 15;
    const int blockRow = blockIdx.x * BM;

    // ---- A staging: thread owns row ar=tid>>2, k-slice aj=(tid&3)*8 ----
    const int ar = tid >> 2;          // 0..127
    const int aj = tid & 3;           // 0..3 (8 floats each)
    const int a_mt = ar >> 4, a_r16 = ar & 15;
    const int a_woff = a_mt * 512 + ((a_r16 ^ (aj << 2)) + aj * 16) * 8;
    const float* ag = Afp + (size_t)(blockRow + ar) * D + aj * 8;

    // ---- A fragment read offsets (buffer-relative u16) ----
    int a_roff[MT];
    #pragma unroll
    for (int mt = 0; mt < MT; ++mt)
        a_roff[mt] = mt * 512 + ((tq ^ (quad << 2)) + quad * 16) * 8;

    // ---- B: direct global loads, wave w owns nt tiles w*4..w*4+3 ----
    const unsigned short* bg[4];
    #pragma unroll
    for (int i = 0; i < 4; ++i)
        bg[i] = Bsw + (size_t)(wave * 4 + i) * 512 + lane * 8;

    f32x4 acc[MT][4];
    #pragma unroll
    for (int mt = 0; mt < MT; ++mt)
        #pragma unroll
        for (int nt = 0; nt < 4; ++nt)
            acc[mt][nt] = (f32x4){0.f, 0.f, 0.f, 0.f};
    float ssq = 0.0f;
    if (tid == 0) blockLoss = 0.0f;

    const int nK = D / BK;   // 32

    // ---- prologue: stage A(0) into buf0, load B(0) into regs ----
    bf16x8 bcur[4];
    {
        float4 v0 = *(const float4*)ag;
        float4 v1 = *(const float4*)(ag + 4);
        #pragma unroll
        for (int i = 0; i < 4; ++i)
            bcur[i] = *(const bf16x8*)bg[i];
        ssq += v0.x*v0.x + v0.y*v0.y + v0.z*v0.z + v0.w*v0.w
             + v1.x*v1.x + v1.y*v1.y + v1.z*v1.z + v1.w*v1.w;
        u16x8 u;
        u[0] = __builtin_bit_cast(unsigned short, __float2bfloat16(v0.x));
        u[1] = __builtin_bit_cast(unsigned short, __float2bfloat16(v0.y));
        u[2] = __builtin_bit_cast(unsigned short, __float2bfloat16(v0.z));
        u[3] = __builtin_bit_cast(unsigned short, __float2bfloat16(v0.w));
        u[4] = __builtin_bit_cast(unsigned short, __float2bfloat16(v1.x));
        u[5] = __builtin_bit_cast(unsigned short, __float2bfloat16(v1.y));
        u[6] = __builtin_bit_cast(unsigned short, __float2bfloat16(v1.z));
        u[7] = __builtin_bit_cast(unsigned short, __float2bfloat16(v1.w));
        *(u16x8*)&sm.A[a_woff] = u;
    }

    for (int kt = 0; kt < nK; ++kt) {
        __syncthreads();   // A buf[kt] visible; buf[kt+1] free
        unsigned short* cur = &sm.A[(kt & 1) * ABUF];
        unsigned short* nxt = &sm.A[((kt + 1) & 1) * ABUF];
        const bool has_next = (kt + 1) < nK;

        float4 v0, v1;
        bf16x8 bnext[4];
        if (has_next) {
            v0 = *(const float4*)(ag + (kt + 1) * BK);       // A prefetch first
            v1 = *(const float4*)(ag + (kt + 1) * BK + 4);
            #pragma unroll
            for (int i = 0; i < 4; ++i)                       // B prefetch (L2)
                bnext[i] = *(const bf16x8*)(bg[i] + (size_t)(kt + 1) * BSTEP);
        }

        bf16x8 af[MT];
        #pragma unroll
        for (int mt = 0; mt < MT; ++mt)
            af[mt] = *(const bf16x8*)(cur + a_roff[mt]);
        #pragma unroll
        for (int mt = 0; mt < MT; ++mt)
            #pragma unroll
            for (int nt = 0; nt < 4; ++nt)
                acc[mt][nt] = __builtin_amdgcn_mfma_f32_16x16x32_bf16(
                    af[mt], bcur[nt], acc[mt][nt], 0, 0, 0);

        if (has_next) {   // A latency hidden behind the MFMA block
            ssq += v0.x*v0.x + v0.y*v0.y + v0.z*v0.z + v0.w*v0.w
                 + v1.x*v1.x + v1.y*v1.y + v1.z*v1.z + v1.w*v1.w;
            u16x8 u;
            u[0] = __builtin_bit_cast(unsigned short, __float2bfloat16(v0.x));
            u[1] = __builtin_bit_cast(unsigned short, __float2bfloat16(v0.y));
            u[2] = __builtin_bit_cast(unsigned short, __float2bfloat16(v0.z));
            u[3] = __builtin_bit_cast(unsigned short, __float2bfloat16(v0.w));
            u[4] = __builtin_bit_cast(unsigned short, __float2bfloat16(v1.x));
            u[5] = __builtin_bit_cast(unsigned short, __float2bfloat16(v1.y));
            u[6] = __builtin_bit_cast(unsigned short, __float2bfloat16(v1.z));
            u[7] = __builtin_bit_cast(unsigned short, __float2bfloat16(v1.w));
            *(u16x8*)(nxt + a_woff) = u;
            #pragma unroll
            for (int i = 0; i < 4; ++i) bcur[i] = bnext[i];
        }
    }

    // ---- row inverse norms: reduce 4 k-slice partials per row ----
    ssq += __shfl_xor(ssq, 1);
    ssq += __shfl_xor(ssq, 2);
    if (aj == 0) inv_e_s[ar] = 1.0f / fmaxf(sqrtf(ssq), EPS);

    // ---- epilogue: scale + per-16-row logsumexp + NLL (8 groups) ----
    float ic[4];
    #pragma unroll
    for (int nt = 0; nt < 4; ++nt)
        ic[nt] = inv_c[wave * 64 + nt * 16 + tq];
    const float invN = 1.0f / (float)N;

    for (int g = 0; g < MT; ++g) {
        __syncthreads();
        float ie[4];
        #pragma unroll
        for (int r = 0; r < 4; ++r)
            ie[r] = inv_e_s[g * 16 + quad * 4 + r];
        #pragma unroll
        for (int nt = 0; nt < 4; ++nt) {
            int col = wave * 64 + nt * 16 + tq;
            #pragma unroll
            for (int r = 0; r < 4; ++r)
                sm.L[(quad * 4 + r) * LSTRIDE + col] = acc[g][nt][r] * ie[r] * ic[nt];
        }
        __syncthreads();
        #pragma unroll
        for (int rr = 0; rr < 2; ++rr) {
            int rl = wave * 2 + rr;
            int grow = blockRow + g * 16 + rl;
            float vals[8];
            float vmax = -3.0e38f;
            #pragma unroll
            for (int j = 0; j < 8; ++j) {
                vals[j] = sm.L[rl * LSTRIDE + j * 64 + lane];
                vmax = fmaxf(vmax, vals[j]);
            }
            #pragma unroll
            for (int off = 32; off; off >>= 1) vmax = fmaxf(vmax, __shfl_xor(vmax, off));
            float s = 0.0f;
            #pragma unroll
            for (int j = 0; j < 8; ++j) s += __expf(vals[j] - vmax);
            #pragma unroll
            for (int off = 32; off; off >>= 1) s += __shfl_xor(s, off);
            if (lane == 0) {
                int lab = labels[grow];
                float ll = sm.L[rl * LSTRIDE + lab];
                atomicAdd(&blockLoss, vmax + __logf(s) - ll);
            }
        }
    }
    __syncthreads();
    if (tid == 0) atomicAdd(out, blockLoss * invN);
}

// ---------------------------------------------------------------------------
extern "C" void kernel_launch(void* const* d_in, const int* in_sizes, int n_in,
                              void* d_out, int out_size, void* d_ws, size_t ws_size,
                              hipStream_t stream)
{
    const float* emb = (const float*)d_in[0];
    const float* cen = (const float*)d_in[1];
    const int* labels = (const int*)d_in[2];
    float* out = (float*)d_out;

    const int N = in_sizes[2];
    const int D = in_sizes[0] / N;
    const int K = in_sizes[1] / D;

    char* ws = (char*)d_ws;
    unsigned short* Bsw = (unsigned short*)ws;              // K*D*2 bytes, swizzled
    float* inv_c = (float*)(ws + (size_t)K * D * 2);        // K floats

    hipMemsetAsync(d_out, 0, sizeof(float), stream);

    prep_centers_kernel<<<(K + 3) / 4, 256, 0, stream>>>(cen, Bsw, inv_c, K, D);

    gemm_loss_kernel<<<N / BM, 512, 0, stream>>>(emb, Bsw, inv_c, labels, out, N, D);
}